// Round 4
// baseline (232.725 us; speedup 1.0000x reference)
//
#include <hip/hip_runtime.h>

// LocalPredictor: 3x3 conv (32->128, center masked) + ReLU + 1x1 conv (128->32)
// B=8, k=32, H=W=256, HID=128. fp32 in/out (values bf16-exact) -> bf16 MFMA.
// v4: independent 2-row x 64-px blocks (grid 4096). One staging burst
// (32 loads/thread, transposing pack, b128 LDS writes), 3 barriers per block
// lifetime, z/h LDS union (34.8 KB). Attacks the v3 latency convoy:
// 138 MB compulsory traffic was moving at only 1.38 TB/s.

#define KC 32
#define HH 256
#define WW 256
#define HID 128

typedef __attribute__((ext_vector_type(8))) short short8;
typedef __attribute__((ext_vector_type(4))) float f32x4;

__device__ __forceinline__ unsigned short f2bf(float f) {
    union { float f; unsigned int i; } x; x.f = f;
    unsigned int r = x.i + 0x7FFFu + ((x.i >> 16) & 1u);  // RNE
    return (unsigned short)(r >> 16);
}

// ws: w1t bf16[9*HID*KC] | w2t bf16[KC*HID].  w1t[p][d][c], c contiguous.
__global__ void prep_weights(const float* __restrict__ w1,
                             const float* __restrict__ w2,
                             unsigned short* __restrict__ w1t,
                             unsigned short* __restrict__ w2t) {
    int i = blockIdx.x * 256 + threadIdx.x;
    if (i < 9 * HID * KC) {
        int c = i & 31;
        int d = (i >> 5) & 127;
        int p = i >> 12;
        w1t[i] = f2bf(w1[d * (9 * KC) + c * 9 + p]);
    } else if (i < 9 * HID * KC + KC * HID) {
        int j = i - 9 * HID * KC;
        w2t[j] = f2bf(w2[j]);
    }
}

union __align__(16) LdsU {
    unsigned short z[4 * 66 * 40];   // [dy 0..3][slot x 0..65][c], c-stride 40
    unsigned short h[128 * 136];     // [m 0..127][d], d-stride 136
};

__global__ __launch_bounds__(256, 3) void local_pred_kernel(
    const float* __restrict__ zg,
    const unsigned short* __restrict__ w1t,
    const float* __restrict__ b1g,
    const unsigned short* __restrict__ w2t,
    const float* __restrict__ b2g,
    float* __restrict__ outg)
{
    __shared__ LdsU u;

    const int tid  = threadIdx.x;
    const int bidx = blockIdx.x;
    const int x0 = (bidx & 3) << 6;            // 4 x-tiles of 64
    const int y0 = ((bidx >> 2) & 127) << 1;   // 128 y-pairs
    const int b  = bidx >> 9;                  // batch 0..7

    const int l = tid & 63;                    // staging x-lane
    const int o = tid >> 6;                    // staging c-octet (0..3)

    const int wave = tid >> 6;
    const int lane = tid & 63;
    const int lr = lane & 15;
    const int lq = lane >> 4;

    const float* zb = zg + (size_t)b * KC * HH * WW;

    // ---------------- staging burst: 4 rows (y0-1 .. y0+2) ----------------
    // main: thread (l=x, o=c-octet): 8 loads per row, all 32 issued in a batch
    float m8[4][8];
#pragma unroll
    for (int dy = 0; dy < 4; ++dy) {
        const int gy = y0 - 1 + dy;
        const bool rowok = (unsigned)gy < (unsigned)HH;
        const float* p = zb + ((size_t)(o * 8) * HH + gy) * WW + x0 + l;
#pragma unroll
        for (int j = 0; j < 8; ++j)
            m8[dy][j] = rowok ? p[(size_t)j * HH * WW] : 0.f;
    }
    // halo: threads 192..223 (o==3, idx<32): (hside, c-octet, row) per thread
    const int hidx  = l;
    const int hside = hidx & 1;
    const int hoc   = (hidx >> 1) & 3;
    const int hdy   = hidx >> 3;               // 0..3
    const bool halo_active = (o == 3) && (hidx < 32);
    float e8[8];
    {
        const int gy  = y0 - 1 + hdy;
        const int ghx = x0 - 1 + hside * 65;
        const bool ok = halo_active && (unsigned)gy < (unsigned)HH &&
                        (unsigned)ghx < (unsigned)WW;
        const float* q = zb + ((size_t)(hoc * 8) * HH + gy) * WW + ghx;
#pragma unroll
        for (int j = 0; j < 8; ++j)
            e8[j] = ok ? q[(size_t)j * HH * WW] : 0.f;
    }
    // pack + b128 LDS writes
#pragma unroll
    for (int dy = 0; dy < 4; ++dy) {
        union { short8 s; unsigned int w[4]; } w;
        union { float f; unsigned int i; } uu[8];
#pragma unroll
        for (int j = 0; j < 8; ++j) uu[j].f = m8[dy][j];
#pragma unroll
        for (int k = 0; k < 4; ++k)
            w.w[k] = __builtin_amdgcn_perm(uu[2 * k + 1].i, uu[2 * k].i, 0x07060302u);
        *(short8*)&u.z[(dy * 66 + l + 1) * 40 + o * 8] = w.s;
    }
    if (halo_active) {
        union { short8 s; unsigned int w[4]; } we;
        union { float f; unsigned int i; } ue[8];
#pragma unroll
        for (int j = 0; j < 8; ++j) ue[j].f = e8[j];
#pragma unroll
        for (int k = 0; k < 4; ++k)
            we.w[k] = __builtin_amdgcn_perm(ue[2 * k + 1].i, ue[2 * k].i, 0x07060302u);
        *(short8*)&u.z[(hdy * 66 + hside * 65) * 40 + hoc * 8] = we.s;
    }

    // per-lane constants (loads overlap the barrier wait)
    float bias1[8];
#pragma unroll
    for (int nt = 0; nt < 8; ++nt) bias1[nt] = b1g[nt * 16 + lr];
    float bias2[2];
#pragma unroll
    for (int nt = 0; nt < 2; ++nt) bias2[nt] = b2g[nt * 16 + lr];

    __syncthreads();   // barrier A: z staged

    // ---------------- GEMM1: M=128 px, N=128 hid, K=8 taps x 32c ----------------
    // wave w: image row (w>>1), x-range (w&1)*32 .. +32
    const int yrow = wave >> 1;
    const int xin0 = (wave & 1) * 32;

    f32x4 acc[2][8];
#pragma unroll
    for (int mt = 0; mt < 2; ++mt)
#pragma unroll
        for (int nt = 0; nt < 8; ++nt)
            acc[mt][nt] = (f32x4){0.f, 0.f, 0.f, 0.f};

    const int tap_di[8] = {0, 0, 0, 1, 1, 2, 2, 2};
    const int tap_dj[8] = {0, 1, 2, 0, 2, 0, 1, 2};
#pragma unroll
    for (int t = 0; t < 8; ++t) {
        const int di = tap_di[t], dj = tap_dj[t];
        const int p  = di * 3 + dj;
        short8 afr[2];
#pragma unroll
        for (int mt = 0; mt < 2; ++mt) {
            const int slot = xin0 + mt * 16 + lr + dj;      // image x = x0-1+slot
            afr[mt] = *(const short8*)&u.z[((yrow + di) * 66 + slot) * 40 + lq * 8];
        }
#pragma unroll
        for (int nt = 0; nt < 8; ++nt) {
            short8 bfr = *(const short8*)&w1t[p * (HID * KC) + (nt * 16 + lr) * KC + lq * 8];
#pragma unroll
            for (int mt = 0; mt < 2; ++mt)
                acc[mt][nt] = __builtin_amdgcn_mfma_f32_16x16x32_bf16(
                    afr[mt], bfr, acc[mt][nt], 0, 0, 0);
        }
    }

    __syncthreads();   // barrier C: all GEMM1 z-reads done; LDS reused for h

    // epilogue1: +b1, ReLU, bf16 -> h (C layout: col=lr -> d, row=lq*4+rr -> m)
#pragma unroll
    for (int nt = 0; nt < 8; ++nt) {
        const int d = nt * 16 + lr;
#pragma unroll
        for (int mt = 0; mt < 2; ++mt) {
#pragma unroll
            for (int rr = 0; rr < 4; ++rr) {
                float v = acc[mt][nt][rr] + bias1[nt];
                v = v > 0.f ? v : 0.f;
                const int m = wave * 32 + mt * 16 + lq * 4 + rr;
                u.h[m * 136 + d] = f2bf(v);
            }
        }
    }
    __syncthreads();   // barrier D: h ready

    // ---------------- GEMM2: M=128 px, N=32 out, K=128 ----------------
    f32x4 acc2[2][2];
#pragma unroll
    for (int mt = 0; mt < 2; ++mt)
#pragma unroll
        for (int nt = 0; nt < 2; ++nt)
            acc2[mt][nt] = (f32x4){0.f, 0.f, 0.f, 0.f};
#pragma unroll
    for (int k4 = 0; k4 < 4; ++k4) {
        short8 afr[2];
#pragma unroll
        for (int mt = 0; mt < 2; ++mt) {
            const int m2 = wave * 32 + mt * 16 + lr;
            afr[mt] = *(const short8*)&u.h[m2 * 136 + k4 * 32 + lq * 8];
        }
#pragma unroll
        for (int nt = 0; nt < 2; ++nt) {
            short8 bfr = *(const short8*)&w2t[(nt * 16 + lr) * HID + k4 * 32 + lq * 8];
#pragma unroll
            for (int mt = 0; mt < 2; ++mt)
                acc2[mt][nt] = __builtin_amdgcn_mfma_f32_16x16x32_bf16(
                    afr[mt], bfr, acc2[mt][nt], 0, 0, 0);
        }
    }

    // epilogue2: +b2, 16B coalesced store burst
#pragma unroll
    for (int mt = 0; mt < 2; ++mt) {
#pragma unroll
        for (int nt = 0; nt < 2; ++nt) {
            const int kout = nt * 16 + lr;
            const int m = wave * 32 + mt * 16 + lq * 4;
            f32x4 pack;
#pragma unroll
            for (int rr = 0; rr < 4; ++rr) pack[rr] = acc2[mt][nt][rr] + bias2[nt];
            const size_t off = ((size_t)(b * KC + kout) * HH + (y0 + (m >> 6))) * WW
                               + x0 + (m & 63);
            *(f32x4*)&outg[off] = pack;
        }
    }
}

extern "C" void kernel_launch(void* const* d_in, const int* in_sizes, int n_in,
                              void* d_out, int out_size, void* d_ws, size_t ws_size,
                              hipStream_t stream)
{
    const float* z  = (const float*)d_in[0];
    const float* W1 = (const float*)d_in[1];
    const float* b1 = (const float*)d_in[2];
    const float* W2 = (const float*)d_in[3];
    const float* b2 = (const float*)d_in[4];
    float* out = (float*)d_out;
    unsigned short* w1t = (unsigned short*)d_ws;                // 73728 B
    unsigned short* w2t = (unsigned short*)d_ws + 9 * HID * KC; // + 8192 B

    hipLaunchKernelGGL(prep_weights, dim3(160), dim3(256), 0, stream, W1, W2, w1t, w2t);
    hipLaunchKernelGGL(local_pred_kernel, dim3(8 * 128 * 4), dim3(256), 0, stream,
                       z, w1t, b1, w2t, b2, out);
}

// Round 5
// 210.463 us; speedup vs baseline: 1.1058x; 1.1058x over previous
//
#include <hip/hip_runtime.h>

// LocalPredictor: 3x3 conv (32->128, center masked) + ReLU + 1x1 conv (128->32)
// B=8, k=32, H=W=256, HID=128. fp32 in/out (values bf16-exact) -> bf16 MFMA.
// v5 = v3 (8-row strip, ring buffer; best measured 102us) +
//  (1) raw s_barrier (inline asm, lgkmcnt(0) only) so prefetched global loads
//      survive barriers (__syncthreads drains vmcnt(0) -- m97),
//  (2) prefetch distance 2 (4-slot ring, parity double-buffered reg batches,
//      fully unrolled row loop),
//  (3) far-halo pre-staged once into LDS; per-wave distinct N-quarter in GEMM1
//      (no B-frag duplication); __launch_bounds__(256,4) -> 4 blocks/CU.

#define KC 32
#define HH 256
#define WW 256
#define HID 128
#define YS 8
#define ZROW 2640   // 66 cols * 40 (c-stride)

typedef __attribute__((ext_vector_type(8))) short short8;
typedef __attribute__((ext_vector_type(4))) float f32x4;

// LDS-visibility barrier WITHOUT vmcnt drain: this wave's DS ops complete,
// then sync. Global loads/stores stay in flight across it.
#define BARRIER() asm volatile("s_waitcnt lgkmcnt(0)\n\ts_barrier" ::: "memory")
#define SCHED_FENCE() asm volatile("" ::: "memory")

__device__ __forceinline__ unsigned short f2bf(float f) {
    union { float f; unsigned int i; } x; x.f = f;
    unsigned int r = x.i + 0x7FFFu + ((x.i >> 16) & 1u);  // RNE
    return (unsigned short)(r >> 16);
}

// pack 8 bf16-exact floats -> short8 (truncate = exact)
__device__ __forceinline__ short8 pack8(const float* v) {
    union { short8 s; unsigned int u[4]; } w;
    union { float f; unsigned int i; } uu[8];
#pragma unroll
    for (int j = 0; j < 8; ++j) uu[j].f = v[j];
#pragma unroll
    for (int k = 0; k < 4; ++k)
        w.u[k] = __builtin_amdgcn_perm(uu[2 * k + 1].i, uu[2 * k].i, 0x07060302u);
    return w.s;
}

// ws: w1t bf16[9*HID*KC] | w2t bf16[KC*HID].  w1t[p][d][c], c contiguous.
__global__ void prep_weights(const float* __restrict__ w1,
                             const float* __restrict__ w2,
                             unsigned short* __restrict__ w1t,
                             unsigned short* __restrict__ w2t) {
    int i = blockIdx.x * 256 + threadIdx.x;
    if (i < 9 * HID * KC) {
        int c = i & 31;
        int d = (i >> 5) & 127;
        int p = i >> 12;
        w1t[i] = f2bf(w1[d * (9 * KC) + c * 9 + p]);
    } else if (i < 9 * HID * KC + KC * HID) {
        int j = i - 9 * HID * KC;
        w2t[j] = f2bf(w2[j]);
    }
}

__global__ __launch_bounds__(256, 4) void local_pred_kernel(
    const float* __restrict__ zg,
    const unsigned short* __restrict__ w1t,
    const float* __restrict__ b1g,
    const unsigned short* __restrict__ w2t,
    const float* __restrict__ b2g,
    float* __restrict__ outg)
{
    __shared__ __attribute__((aligned(16))) unsigned short z_lds[4 * ZROW];   // 21120 B
    __shared__ __attribute__((aligned(16))) unsigned short h_lds[64 * 136];   // 17408 B
    __shared__ __attribute__((aligned(16))) unsigned short halo_lds[7 * 2 * 32]; // 896 B

    const int tid  = threadIdx.x;
    const int bidx = blockIdx.x;
    const int x0 = (bidx & 3) << 6;
    const int y0 = ((bidx >> 2) & 31) * YS;
    const int b  = bidx >> 7;

    const int l = tid & 63;       // staging x-lane
    const int o = tid >> 6;       // staging c-octet

    const int wave = tid >> 6;
    const int lane = tid & 63;
    const int lr = lane & 15;
    const int lq = lane >> 4;

    const float* zb = zg + (size_t)b * KC * HH * WW;

    // ---------------- prestage burst ----------------
    // main rows y0-1..y0+1
    float p8[3][8];
#pragma unroll
    for (int dy = 0; dy < 3; ++dy) {
        const int gy = y0 - 1 + dy;
        const bool ok = (unsigned)gy < (unsigned)HH;
        const int gyc = ok ? gy : 0;
        const float* p = zb + ((size_t)(o * 8) * HH + gyc) * WW + x0 + l;
#pragma unroll
        for (int j = 0; j < 8; ++j) p8[dy][j] = ok ? p[(size_t)j * HH * WW] : 0.f;
    }
    // near halo (rows y0-1..y0+1): tid<24 -> (side, c-octet, dy)
    const int nhs = tid & 1, nho = (tid >> 1) & 3, nhd = tid >> 3;
    float nh8[8];
    {
        const int gy = y0 - 1 + nhd;
        const int gx = x0 - 1 + nhs * 65;
        const bool ok = (tid < 24) && ((unsigned)gy < (unsigned)HH) &&
                        ((unsigned)gx < (unsigned)WW);
        const int gyc = ok ? gy : 0, gxc = ok ? gx : 0;
        const float* q = zb + ((size_t)(nho * 8) * HH + gyc) * WW + gxc;
#pragma unroll
        for (int j = 0; j < 8; ++j) nh8[j] = ok ? q[(size_t)j * HH * WW] : 0.f;
    }
    // far halo (rows y0+2..y0+8): tid in [64,120) -> (side, c-octet, row)
    const int fidx = tid - 64;
    const int fhs = fidx & 1, fho = (fidx >> 1) & 3, fhr = fidx >> 3;
    float fh8[8];
    {
        const int gy = y0 + 2 + fhr;
        const int gx = x0 - 1 + fhs * 65;
        const bool ok = (tid >= 64) && (tid < 120) && (gy < HH) &&
                        ((unsigned)gx < (unsigned)WW);
        const int gyc = ok ? gy : 0, gxc = ok ? gx : 0;
        const float* q = zb + ((size_t)(fho * 8) * HH + gyc) * WW + gxc;
#pragma unroll
        for (int j = 0; j < 8; ++j) fh8[j] = ok ? q[(size_t)j * HH * WW] : 0.f;
    }
    // first prefetch batch: row y0+2 (always in range: y0 <= 248)
    float mv[2][8];
    {
        const float* p = zb + ((size_t)(o * 8) * HH + (y0 + 2)) * WW + x0 + l;
#pragma unroll
        for (int j = 0; j < 8; ++j) mv[0][j] = p[(size_t)j * HH * WW];
    }
    // commits (packs wait only on their own loads; mv[0] stays in flight)
#pragma unroll
    for (int dy = 0; dy < 3; ++dy)
        *(short8*)&z_lds[(dy * 66 + l + 1) * 40 + o * 8] = pack8(p8[dy]);
    if (tid < 24)
        *(short8*)&z_lds[(nhd * 66 + nhs * 65) * 40 + nho * 8] = pack8(nh8);
    if (tid >= 64 && tid < 120)
        *(short8*)&halo_lds[(fhr * 2 + fhs) * 32 + fho * 8] = pack8(fh8);

    // per-strip constants
    float bias1[2], bias2[2];
#pragma unroll
    for (int nt = 0; nt < 2; ++nt) bias1[nt] = b1g[wave * 32 + nt * 16 + lr];
#pragma unroll
    for (int nt = 0; nt < 2; ++nt) bias2[nt] = b2g[nt * 16 + lr];
    short8 w2f[4][2];   // hoisted: keeps GEMM2 free of global loads
#pragma unroll
    for (int k4 = 0; k4 < 4; ++k4)
#pragma unroll
        for (int nt = 0; nt < 2; ++nt)
            w2f[k4][nt] = *(const short8*)&w2t[(nt * 16 + lr) * HID + k4 * 32 + lq * 8];

    BARRIER();

    const int tap_di[8] = {0, 0, 0, 1, 1, 2, 2, 2};
    const int tap_dj[8] = {0, 1, 2, 0, 2, 0, 1, 2};

#pragma unroll
    for (int r = 0; r < YS; ++r) {
        const int y = y0 + r;
        const int S0 = r & 3, S1 = (r + 1) & 3, S2 = (r + 2) & 3, S3 = (r + 3) & 3;

        // ---------- GEMM1: per wave M=64 (mt 0..3), N=32 (wave quarter, nt 0..1) ----------
        f32x4 acc[4][2];
#pragma unroll
        for (int mt = 0; mt < 4; ++mt)
#pragma unroll
            for (int nt = 0; nt < 2; ++nt)
                acc[mt][nt] = (f32x4){0.f, 0.f, 0.f, 0.f};

        const int rowoff[3] = {S0 * ZROW, S1 * ZROW, S2 * ZROW};
#pragma unroll
        for (int t = 0; t < 8; ++t) {
            const int di = tap_di[t], dj = tap_dj[t];
            const int p = di * 3 + dj;
            short8 afr[4];
#pragma unroll
            for (int mt = 0; mt < 4; ++mt)
                afr[mt] = *(const short8*)&z_lds[rowoff[di] + (mt * 16 + lr + dj) * 40 + lq * 8];
            short8 bfr[2];
#pragma unroll
            for (int nt = 0; nt < 2; ++nt)
                bfr[nt] = *(const short8*)&w1t[p * (HID * KC) + (wave * 32 + nt * 16 + lr) * KC + lq * 8];
#pragma unroll
            for (int nt = 0; nt < 2; ++nt)
#pragma unroll
                for (int mt = 0; mt < 4; ++mt)
                    acc[mt][nt] = __builtin_amdgcn_mfma_f32_16x16x32_bf16(
                        afr[mt], bfr[nt], acc[mt][nt], 0, 0, 0);
        }

        SCHED_FENCE();
        // ---------- issue prefetch for row y+3 (commits at end of iter r+1) ----------
        if (r < 6) {
            const int gy = y + 3;
            const bool ok = gy < HH;
            const int gyc = ok ? gy : 0;
            const float* p = zb + ((size_t)(o * 8) * HH + gyc) * WW + x0 + l;
#pragma unroll
            for (int j = 0; j < 8; ++j) mv[(r + 1) & 1][j] = ok ? p[(size_t)j * HH * WW] : 0.f;
        }
        SCHED_FENCE();

        // ---------- epilogue1: +b1, ReLU, bf16 -> h ----------
#pragma unroll
        for (int nt = 0; nt < 2; ++nt) {
            const int d = wave * 32 + nt * 16 + lr;
#pragma unroll
            for (int mt = 0; mt < 4; ++mt)
#pragma unroll
                for (int rr = 0; rr < 4; ++rr) {
                    float v = acc[mt][nt][rr] + bias1[nt];
                    v = v > 0.f ? v : 0.f;
                    const int m = mt * 16 + lq * 4 + rr;
                    h_lds[m * 136 + d] = f2bf(v);
                }
        }
        BARRIER();   // h ready; GEMM1 z-reads of all waves complete

        // ---------- GEMM2: M=64, N=32, K=128 (no global loads) ----------
        f32x4 acc2[2];
        acc2[0] = (f32x4){0.f, 0.f, 0.f, 0.f};
        acc2[1] = (f32x4){0.f, 0.f, 0.f, 0.f};
        const int m2 = wave * 16 + lr;
#pragma unroll
        for (int k4 = 0; k4 < 4; ++k4) {
            short8 afr = *(const short8*)&h_lds[m2 * 136 + k4 * 32 + lq * 8];
#pragma unroll
            for (int nt = 0; nt < 2; ++nt)
                acc2[nt] = __builtin_amdgcn_mfma_f32_16x16x32_bf16(
                    afr, w2f[k4][nt], acc2[nt], 0, 0, 0);
        }

        // ---------- epilogue2: +b2, 16B coalesced stores ----------
#pragma unroll
        for (int nt = 0; nt < 2; ++nt) {
            const int kout = nt * 16 + lr;
            f32x4 pk;
#pragma unroll
            for (int rr = 0; rr < 4; ++rr) pk[rr] = acc2[nt][rr] + bias2[nt];
            const int mb = wave * 16 + lq * 4;
            const size_t off = ((size_t)(b * KC + kout) * HH + y) * WW + x0 + mb;
            *(f32x4*)&outg[off] = pk;
        }

        // ---------- commit row y+2 (issued one iter ago) into slot S3 ----------
        if (r < 7) {
            *(short8*)&z_lds[(S3 * 66 + l + 1) * 40 + o * 8] = pack8(mv[r & 1]);
            if (tid < 8) {
                const int side = tid & 1, oct = tid >> 1;
                short8 hv = *(const short8*)&halo_lds[(r * 2 + side) * 32 + oct * 8];
                *(short8*)&z_lds[(S3 * 66 + side * 65) * 40 + oct * 8] = hv;
            }
        }
        BARRIER();   // commit visible; h-reads done (h rewritten next iter)
    }
}

extern "C" void kernel_launch(void* const* d_in, const int* in_sizes, int n_in,
                              void* d_out, int out_size, void* d_ws, size_t ws_size,
                              hipStream_t stream)
{
    const float* z  = (const float*)d_in[0];
    const float* W1 = (const float*)d_in[1];
    const float* b1 = (const float*)d_in[2];
    const float* W2 = (const float*)d_in[3];
    const float* b2 = (const float*)d_in[4];
    float* out = (float*)d_out;
    unsigned short* w1t = (unsigned short*)d_ws;                // 73728 B
    unsigned short* w2t = (unsigned short*)d_ws + 9 * HID * KC; // + 8192 B

    hipLaunchKernelGGL(prep_weights, dim3(160), dim3(256), 0, stream, W1, W2, w1t, w2t);
    hipLaunchKernelGGL(local_pred_kernel, dim3(8 * 4 * (HH / YS)), dim3(256), 0, stream,
                       z, w1t, b1, w2t, b2, out);
}

// Round 6
// 174.925 us; speedup vs baseline: 1.3304x; 1.2032x over previous
//
#include <hip/hip_runtime.h>

// LocalPredictor: 3x3 conv (32->128, center masked) + ReLU + 1x1 conv (128->32)
// B=8, k=32, H=W=256, HID=128. fp32 in/out (values bf16-exact) -> bf16 MFMA.
// v6 = v5's raw-barrier pipeline, register-lean (v5 spilled: VGPR=64 cap ->
// +140MB fetch / +51MB write of scratch traffic):
//  - distance-1 prefetch, single mv8 buffer (issue at iter top, commit after stores)
//  - GEMM2 B-frags reloaded from L1-hot w2t each iter (no 32-VGPR hoist)
//  - sequential fenced prologue rounds (caps register high-water mark)
//  - __launch_bounds__(256,3): no forced spills; LDS (39.4KB) still allows 4/CU

#define KC 32
#define HH 256
#define WW 256
#define HID 128
#define YS 8
#define ZROW 2640   // 66 cols * 40 (c-stride)

typedef __attribute__((ext_vector_type(8))) short short8;
typedef __attribute__((ext_vector_type(4))) float f32x4;

// LDS-visibility barrier WITHOUT vmcnt drain: global loads/stores stay in flight.
#define BARRIER() asm volatile("s_waitcnt lgkmcnt(0)\n\ts_barrier" ::: "memory")
#define SCHED_FENCE() asm volatile("" ::: "memory")

__device__ __forceinline__ unsigned short f2bf(float f) {
    union { float f; unsigned int i; } x; x.f = f;
    unsigned int r = x.i + 0x7FFFu + ((x.i >> 16) & 1u);  // RNE
    return (unsigned short)(r >> 16);
}

// pack 8 bf16-exact floats -> short8 (truncate = exact)
__device__ __forceinline__ short8 pack8(const float* v) {
    union { short8 s; unsigned int u[4]; } w;
    union { float f; unsigned int i; } uu[8];
#pragma unroll
    for (int j = 0; j < 8; ++j) uu[j].f = v[j];
#pragma unroll
    for (int k = 0; k < 4; ++k)
        w.u[k] = __builtin_amdgcn_perm(uu[2 * k + 1].i, uu[2 * k].i, 0x07060302u);
    return w.s;
}

// ws: w1t bf16[9*HID*KC] | w2t bf16[KC*HID].  w1t[p][d][c], c contiguous.
__global__ void prep_weights(const float* __restrict__ w1,
                             const float* __restrict__ w2,
                             unsigned short* __restrict__ w1t,
                             unsigned short* __restrict__ w2t) {
    int i = blockIdx.x * 256 + threadIdx.x;
    if (i < 9 * HID * KC) {
        int c = i & 31;
        int d = (i >> 5) & 127;
        int p = i >> 12;
        w1t[i] = f2bf(w1[d * (9 * KC) + c * 9 + p]);
    } else if (i < 9 * HID * KC + KC * HID) {
        int j = i - 9 * HID * KC;
        w2t[j] = f2bf(w2[j]);
    }
}

__global__ __launch_bounds__(256, 3) void local_pred_kernel(
    const float* __restrict__ zg,
    const unsigned short* __restrict__ w1t,
    const float* __restrict__ b1g,
    const unsigned short* __restrict__ w2t,
    const float* __restrict__ b2g,
    float* __restrict__ outg)
{
    __shared__ __attribute__((aligned(16))) unsigned short z_lds[4 * ZROW];      // 21120 B
    __shared__ __attribute__((aligned(16))) unsigned short h_lds[64 * 136];      // 17408 B
    __shared__ __attribute__((aligned(16))) unsigned short halo_lds[7 * 2 * 32]; //   896 B

    const int tid  = threadIdx.x;
    const int bidx = blockIdx.x;
    const int x0 = (bidx & 3) << 6;
    const int y0 = ((bidx >> 2) & 31) * YS;
    const int b  = bidx >> 7;

    const int l = tid & 63;       // staging x-lane
    const int o = tid >> 6;       // staging c-octet

    const int wave = tid >> 6;
    const int lane = tid & 63;
    const int lr = lane & 15;
    const int lq = lane >> 4;

    const float* zb = zg + (size_t)b * KC * HH * WW;

    // ---------------- prologue: sequential fenced rounds (low reg pressure) ----------------
    // main rows y0-1 .. y0+1
#pragma unroll
    for (int dy = 0; dy < 3; ++dy) {
        const int gy = y0 - 1 + dy;
        const bool ok = (unsigned)gy < (unsigned)HH;
        const int gyc = ok ? gy : 0;
        const float* p = zb + ((size_t)(o * 8) * HH + gyc) * WW + x0 + l;
        float t8[8];
#pragma unroll
        for (int j = 0; j < 8; ++j) t8[j] = ok ? p[(size_t)j * HH * WW] : 0.f;
        *(short8*)&z_lds[(dy * 66 + l + 1) * 40 + o * 8] = pack8(t8);
        SCHED_FENCE();
    }
    // near halo (rows y0-1..y0+1): tid<24 -> (side, c-octet, dy)
    {
        const int s = tid & 1, oc = (tid >> 1) & 3, dy = tid >> 3;
        const int gy = y0 - 1 + dy;
        const int gx = x0 - 1 + s * 65;
        const bool ok = (tid < 24) && ((unsigned)gy < (unsigned)HH) &&
                        ((unsigned)gx < (unsigned)WW);
        const float* q = zb + ((size_t)(oc * 8) * HH + (ok ? gy : 0)) * WW + (ok ? gx : 0);
        float t8[8];
#pragma unroll
        for (int j = 0; j < 8; ++j) t8[j] = ok ? q[(size_t)j * HH * WW] : 0.f;
        if (tid < 24)
            *(short8*)&z_lds[(dy * 66 + s * 65) * 40 + oc * 8] = pack8(t8);
        SCHED_FENCE();
    }
    // far halo (rows y0+2..y0+8): tid in [64,120) -> (side, c-octet, row)
    {
        const int fi = tid - 64;
        const int s = fi & 1, oc = (fi >> 1) & 3, fr = fi >> 3;
        const int gy = y0 + 2 + fr;
        const int gx = x0 - 1 + s * 65;
        const bool ok = (tid >= 64) && (tid < 120) && (gy < HH) &&
                        ((unsigned)gx < (unsigned)WW);
        const float* q = zb + ((size_t)(oc * 8) * HH + (ok ? gy : 0)) * WW + (ok ? gx : 0);
        float t8[8];
#pragma unroll
        for (int j = 0; j < 8; ++j) t8[j] = ok ? q[(size_t)j * HH * WW] : 0.f;
        if (tid >= 64 && tid < 120)
            *(short8*)&halo_lds[(fr * 2 + s) * 32 + oc * 8] = pack8(t8);
        SCHED_FENCE();
    }

    // hoisted biases (4 regs)
    float bias1[2], bias2[2];
#pragma unroll
    for (int nt = 0; nt < 2; ++nt) bias1[nt] = b1g[wave * 32 + nt * 16 + lr];
#pragma unroll
    for (int nt = 0; nt < 2; ++nt) bias2[nt] = b2g[nt * 16 + lr];

    BARRIER();

    const int tap_di[8] = {0, 0, 0, 1, 1, 2, 2, 2};
    const int tap_dj[8] = {0, 1, 2, 0, 2, 0, 1, 2};

    float mv8[8];   // single distance-1 prefetch buffer

#pragma unroll
    for (int r = 0; r < YS; ++r) {
        const int y = y0 + r;
        const int S0 = r & 3, S1 = (r + 1) & 3, S2 = (r + 2) & 3, S3 = (r + 3) & 3;

        // ---------- issue prefetch: row y+2 (consumed at commit, end of this iter) ----------
        if (r < 7) {
            const int gy = y + 2;
            const bool ok = gy < HH;
            const float* p = zb + ((size_t)(o * 8) * HH + (ok ? gy : 0)) * WW + x0 + l;
#pragma unroll
            for (int j = 0; j < 8; ++j) mv8[j] = ok ? p[(size_t)j * HH * WW] : 0.f;
        }
        SCHED_FENCE();

        // ---------- GEMM1: per wave M=64 (mt 0..3), N=32 quarter (nt 0..1) ----------
        f32x4 acc[4][2];
#pragma unroll
        for (int mt = 0; mt < 4; ++mt)
#pragma unroll
            for (int nt = 0; nt < 2; ++nt)
                acc[mt][nt] = (f32x4){0.f, 0.f, 0.f, 0.f};

        const int rowoff[3] = {S0 * ZROW, S1 * ZROW, S2 * ZROW};
#pragma unroll
        for (int t = 0; t < 8; ++t) {
            const int di = tap_di[t], dj = tap_dj[t];
            const int p = di * 3 + dj;
            short8 afr[4];
#pragma unroll
            for (int mt = 0; mt < 4; ++mt)
                afr[mt] = *(const short8*)&z_lds[rowoff[di] + (mt * 16 + lr + dj) * 40 + lq * 8];
            short8 bfr[2];
#pragma unroll
            for (int nt = 0; nt < 2; ++nt)
                bfr[nt] = *(const short8*)&w1t[p * (HID * KC) + (wave * 32 + nt * 16 + lr) * KC + lq * 8];
#pragma unroll
            for (int nt = 0; nt < 2; ++nt)
#pragma unroll
                for (int mt = 0; mt < 4; ++mt)
                    acc[mt][nt] = __builtin_amdgcn_mfma_f32_16x16x32_bf16(
                        afr[mt], bfr[nt], acc[mt][nt], 0, 0, 0);
        }

        // ---------- epilogue1: +b1, ReLU, bf16 -> h ----------
#pragma unroll
        for (int nt = 0; nt < 2; ++nt) {
            const int d = wave * 32 + nt * 16 + lr;
#pragma unroll
            for (int mt = 0; mt < 4; ++mt)
#pragma unroll
                for (int rr = 0; rr < 4; ++rr) {
                    float v = acc[mt][nt][rr] + bias1[nt];
                    v = v > 0.f ? v : 0.f;
                    const int m = mt * 16 + lq * 4 + rr;
                    h_lds[m * 136 + d] = f2bf(v);
                }
        }
        BARRIER();   // h ready; all waves' GEMM1 z-reads complete

        // ---------- GEMM2: M=64, N=32, K=128 (B from L1-hot w2t) ----------
        f32x4 acc2[2];
        acc2[0] = (f32x4){0.f, 0.f, 0.f, 0.f};
        acc2[1] = (f32x4){0.f, 0.f, 0.f, 0.f};
        const int m2 = wave * 16 + lr;
#pragma unroll
        for (int k4 = 0; k4 < 4; ++k4) {
            short8 afr = *(const short8*)&h_lds[m2 * 136 + k4 * 32 + lq * 8];
#pragma unroll
            for (int nt = 0; nt < 2; ++nt) {
                short8 bfr = *(const short8*)&w2t[(nt * 16 + lr) * HID + k4 * 32 + lq * 8];
                acc2[nt] = __builtin_amdgcn_mfma_f32_16x16x32_bf16(afr, bfr, acc2[nt], 0, 0, 0);
            }
        }

        // ---------- epilogue2: +b2, 16B coalesced stores ----------
#pragma unroll
        for (int nt = 0; nt < 2; ++nt) {
            const int kout = nt * 16 + lr;
            f32x4 pk;
#pragma unroll
            for (int rr = 0; rr < 4; ++rr) pk[rr] = acc2[nt][rr] + bias2[nt];
            const int mb = wave * 16 + lq * 4;
            const size_t off = ((size_t)(b * KC + kout) * HH + y) * WW + x0 + mb;
            *(f32x4*)&outg[off] = pk;
        }

        // ---------- commit prefetched row y+2 into slot S3 ----------
        if (r < 7) {
            *(short8*)&z_lds[(S3 * 66 + l + 1) * 40 + o * 8] = pack8(mv8);
            if (tid < 8) {
                const int side = tid & 1, oct = tid >> 1;
                short8 hv = *(const short8*)&halo_lds[(r * 2 + side) * 32 + oct * 8];
                *(short8*)&z_lds[(S3 * 66 + side * 65) * 40 + oct * 8] = hv;
            }
        }
        BARRIER();   // commit visible; h-reads done (h rewritten next iter)
    }
}

extern "C" void kernel_launch(void* const* d_in, const int* in_sizes, int n_in,
                              void* d_out, int out_size, void* d_ws, size_t ws_size,
                              hipStream_t stream)
{
    const float* z  = (const float*)d_in[0];
    const float* W1 = (const float*)d_in[1];
    const float* b1 = (const float*)d_in[2];
    const float* W2 = (const float*)d_in[3];
    const float* b2 = (const float*)d_in[4];
    float* out = (float*)d_out;
    unsigned short* w1t = (unsigned short*)d_ws;                // 73728 B
    unsigned short* w2t = (unsigned short*)d_ws + 9 * HID * KC; // + 8192 B

    hipLaunchKernelGGL(prep_weights, dim3(160), dim3(256), 0, stream, W1, W2, w1t, w2t);
    hipLaunchKernelGGL(local_pred_kernel, dim3(8 * 4 * (HH / YS)), dim3(256), 0, stream,
                       z, w1t, b1, w2t, b2, out);
}